// Round 1
// baseline (1885.344 us; speedup 1.0000x reference)
//
#include <hip/hip_runtime.h>

#define CELL 50.0f
#define N_TABLE 1024
#define NPAIRS_BLOCK 256

__global__ __launch_bounds__(NPAIRS_BLOCK) void pair_force_kernel(
    const float* __restrict__ q,
    const int2* __restrict__ nbr,
    const float* __restrict__ table_r,
    const float* __restrict__ table_f,
    float* __restrict__ force,
    int n_pairs)
{
    __shared__ float tr[N_TABLE];
    __shared__ float tf[N_TABLE];
    for (int k = threadIdx.x; k < N_TABLE; k += NPAIRS_BLOCK) {
        tr[k] = table_r[k];
        tf[k] = table_f[k];
    }
    __syncthreads();

    const float r0   = tr[0];
    const float rend = tr[N_TABLE - 1];
    const float inv_dr = (float)(N_TABLE - 1) / (rend - r0);

    int p = blockIdx.x * NPAIRS_BLOCK + threadIdx.x;
    if (p >= n_pairs) return;

    int2 ij = nbr[p];
    int i = ij.x, j = ij.y;

    float dx = q[3 * i + 0] - q[3 * j + 0];
    float dy = q[3 * i + 1] - q[3 * j + 1];
    float dz = q[3 * i + 2] - q[3 * j + 2];

    // minimum image: d - CELL * round(d / CELL); rintf = round-half-even (jnp.round)
    dx -= CELL * rintf(dx / CELL);
    dy -= CELL * rintf(dy / CELL);
    dz -= CELL * rintf(dz / CELL);

    float r2 = dx * dx + dy * dy + dz * dz;
    float r  = sqrtf(r2);
    float inv = 1.0f / fmaxf(r, 1e-12f);

    // jnp.interp on uniform grid: direct index + one-step fixup vs actual table_r
    float fm;
    if (r <= r0) {
        fm = tf[0];
    } else if (r >= rend) {
        fm = tf[N_TABLE - 1];
    } else {
        float t = (r - r0) * inv_dr;
        int idx = (int)t;
        idx = min(max(idx, 0), N_TABLE - 2);
        if (r < tr[idx])            idx = max(idx - 1, 0);
        else if (r >= tr[idx + 1])  idx = min(idx + 1, N_TABLE - 2);
        float rl = tr[idx], rh = tr[idx + 1];
        fm = tf[idx] + (r - rl) * (tf[idx + 1] - tf[idx]) / (rh - rl);
    }

    float s  = fm * inv;
    float fx = s * dx, fy = s * dy, fz = s * dz;

    atomicAdd(&force[3 * i + 0], fx);
    atomicAdd(&force[3 * i + 1], fy);
    atomicAdd(&force[3 * i + 2], fz);
    atomicAdd(&force[3 * j + 0], -fx);
    atomicAdd(&force[3 * j + 1], -fy);
    atomicAdd(&force[3 * j + 2], -fz);
}

extern "C" void kernel_launch(void* const* d_in, const int* in_sizes, int n_in,
                              void* d_out, int out_size, void* d_ws, size_t ws_size,
                              hipStream_t stream) {
    const float* q       = (const float*)d_in[0];
    const int2*  nbr     = (const int2*)d_in[1];
    const float* table_r = (const float*)d_in[2];
    const float* table_f = (const float*)d_in[3];
    float*       force   = (float*)d_out;

    const int n_pairs = in_sizes[1] / 2;

    // d_out is poisoned with 0xAA before timing and never re-zeroed: zero it each call.
    hipMemsetAsync(d_out, 0, (size_t)out_size * sizeof(float), stream);

    int blocks = (n_pairs + NPAIRS_BLOCK - 1) / NPAIRS_BLOCK;
    pair_force_kernel<<<blocks, NPAIRS_BLOCK, 0, stream>>>(
        q, nbr, table_r, table_f, force, n_pairs);
}

// Round 2
// 444.399 us; speedup vs baseline: 4.2425x; 4.2425x over previous
//
#include <hip/hip_runtime.h>

#define CELL 50.0f
#define N_TABLE 1024
#define NB 1024            // buckets of 128 atoms each (max 131072 atoms)
#define NBLK 1024          // histogram/scatter blocks
#define THREADS 256

typedef unsigned int uint;

// ---------------- K1: per-block bucket histogram ----------------
__global__ __launch_bounds__(THREADS) void hist_kernel(
    const int2* __restrict__ nbr, uint* __restrict__ partial, int n_pairs, int ppb)
{
    __shared__ uint h[NB];
    for (int k = threadIdx.x; k < NB; k += THREADS) h[k] = 0;
    __syncthreads();
    int start = blockIdx.x * ppb;
    int end   = min(start + ppb, n_pairs);
    for (int p = start + threadIdx.x; p < end; p += THREADS) {
        int2 ij = nbr[p];
        atomicAdd(&h[((uint)ij.x) >> 7], 1u);
        atomicAdd(&h[((uint)ij.y) >> 7], 1u);
    }
    __syncthreads();
    for (int k = threadIdx.x; k < NB; k += THREADS)
        partial[k * NBLK + blockIdx.x] = h[k];
}

// ---------------- K2a: per-bucket exclusive scan over block partials ----------------
__global__ __launch_bounds__(THREADS) void scan_rows_kernel(
    uint* __restrict__ partial, uint* __restrict__ binTotal)
{
    __shared__ uint s[THREADS];
    int bin = blockIdx.x;
    uint running = 0;
    for (int c = 0; c < NBLK / THREADS; c++) {
        int idx = bin * NBLK + c * THREADS + threadIdx.x;
        uint v = partial[idx];
        s[threadIdx.x] = v;
        __syncthreads();
        for (int off = 1; off < THREADS; off <<= 1) {
            uint t = (threadIdx.x >= (uint)off) ? s[threadIdx.x - off] : 0u;
            __syncthreads();
            s[threadIdx.x] += t;
            __syncthreads();
        }
        partial[idx] = running + s[threadIdx.x] - v;   // exclusive within bin
        uint csum = s[THREADS - 1];
        __syncthreads();
        running += csum;
    }
    if (threadIdx.x == 0) binTotal[bin] = running;
}

// ---------------- K2b: exclusive scan of bucket totals ----------------
__global__ __launch_bounds__(THREADS) void scan_totals_kernel(
    const uint* __restrict__ binTotal, uint* __restrict__ binBase)
{
    __shared__ uint s[THREADS];
    uint v[4];
    uint sum = 0;
    int base = threadIdx.x * 4;
    for (int k = 0; k < 4; k++) { v[k] = binTotal[base + k]; sum += v[k]; }
    s[threadIdx.x] = sum;
    __syncthreads();
    for (int off = 1; off < THREADS; off <<= 1) {
        uint t = (threadIdx.x >= (uint)off) ? s[threadIdx.x - off] : 0u;
        __syncthreads();
        s[threadIdx.x] += t;
        __syncthreads();
    }
    uint run = s[threadIdx.x] - sum;   // exclusive prefix of this thread's group
    for (int k = 0; k < 4; k++) { binBase[base + k] = run; run += v[k]; }
    if (threadIdx.x == THREADS - 1) binBase[NB] = run;
}

// ---------------- K3: scatter packed entries into bucket segments ----------------
// entry = (other_atom << 7) | (self_atom & 127); self's bucket = self >> 7.
__global__ __launch_bounds__(THREADS) void scatter_kernel(
    const int2* __restrict__ nbr, const uint* __restrict__ partial,
    const uint* __restrict__ binBase, uint* __restrict__ entries,
    int n_pairs, int ppb)
{
    __shared__ uint cur[NB];
    for (int k = threadIdx.x; k < NB; k += THREADS)
        cur[k] = binBase[k] + partial[k * NBLK + blockIdx.x];
    __syncthreads();
    int start = blockIdx.x * ppb;
    int end   = min(start + ppb, n_pairs);
    for (int p = start + threadIdx.x; p < end; p += THREADS) {
        int2 ij = nbr[p];
        uint i = (uint)ij.x, j = (uint)ij.y;
        uint pi = atomicAdd(&cur[i >> 7], 1u);
        entries[pi] = (j << 7) | (i & 127u);
        uint pj = atomicAdd(&cur[j >> 7], 1u);
        entries[pj] = (i << 7) | (j & 127u);
    }
}

// ---------------- K4: per-bucket reduce (recompute force, LDS accumulate) ----------------
__global__ __launch_bounds__(512) void reduce_kernel(
    const float* __restrict__ q, const float* __restrict__ table_r,
    const float* __restrict__ table_f, const uint* __restrict__ binBase,
    const uint* __restrict__ entries, float* __restrict__ force, int n_atoms)
{
    __shared__ float tr[N_TABLE];
    __shared__ float tf[N_TABLE];
    __shared__ float qs[128 * 3];
    __shared__ float acc[128 * 3];

    int b = blockIdx.x;
    int atomBase = b << 7;
    if (atomBase >= n_atoms) return;
    int nA = min(128, n_atoms - atomBase);

    for (int k = threadIdx.x; k < N_TABLE; k += 512) { tr[k] = table_r[k]; tf[k] = table_f[k]; }
    for (int k = threadIdx.x; k < nA * 3; k += 512) { qs[k] = q[atomBase * 3 + k]; acc[k] = 0.0f; }
    __syncthreads();

    const float r0   = tr[0];
    const float rend = tr[N_TABLE - 1];
    const float inv_dr = (float)(N_TABLE - 1) / (rend - r0);

    uint e0 = binBase[b], e1 = binBase[b + 1];
    for (uint e = e0 + threadIdx.x; e < e1; e += 512) {
        uint v = entries[e];
        int local = (int)(v & 127u);
        int other = (int)(v >> 7);

        float dx = qs[local * 3 + 0] - q[other * 3 + 0];
        float dy = qs[local * 3 + 1] - q[other * 3 + 1];
        float dz = qs[local * 3 + 2] - q[other * 3 + 2];

        dx -= CELL * rintf(dx / CELL);
        dy -= CELL * rintf(dy / CELL);
        dz -= CELL * rintf(dz / CELL);

        float r   = sqrtf(dx * dx + dy * dy + dz * dz);
        float inv = 1.0f / fmaxf(r, 1e-12f);

        float fm;
        if (r <= r0) {
            fm = tf[0];
        } else if (r >= rend) {
            fm = tf[N_TABLE - 1];
        } else {
            float t = (r - r0) * inv_dr;
            int idx = (int)t;
            idx = min(max(idx, 0), N_TABLE - 2);
            if (r < tr[idx])           idx = max(idx - 1, 0);
            else if (r >= tr[idx + 1]) idx = min(idx + 1, N_TABLE - 2);
            float rl = tr[idx], rh = tr[idx + 1];
            fm = tf[idx] + (r - rl) * (tf[idx + 1] - tf[idx]) / (rh - rl);
        }

        float s = fm * inv;
        atomicAdd(&acc[local * 3 + 0], s * dx);
        atomicAdd(&acc[local * 3 + 1], s * dy);
        atomicAdd(&acc[local * 3 + 2], s * dz);
    }
    __syncthreads();
    for (int k = threadIdx.x; k < nA * 3; k += 512)
        force[atomBase * 3 + k] = acc[k];
}

// ---------------- fallback: proven global-atomic kernel ----------------
__global__ __launch_bounds__(THREADS) void pair_force_atomic_kernel(
    const float* __restrict__ q, const int2* __restrict__ nbr,
    const float* __restrict__ table_r, const float* __restrict__ table_f,
    float* __restrict__ force, int n_pairs)
{
    __shared__ float tr[N_TABLE];
    __shared__ float tf[N_TABLE];
    for (int k = threadIdx.x; k < N_TABLE; k += THREADS) { tr[k] = table_r[k]; tf[k] = table_f[k]; }
    __syncthreads();
    const float r0 = tr[0], rend = tr[N_TABLE - 1];
    const float inv_dr = (float)(N_TABLE - 1) / (rend - r0);
    int p = blockIdx.x * THREADS + threadIdx.x;
    if (p >= n_pairs) return;
    int2 ij = nbr[p];
    int i = ij.x, j = ij.y;
    float dx = q[3 * i] - q[3 * j], dy = q[3 * i + 1] - q[3 * j + 1], dz = q[3 * i + 2] - q[3 * j + 2];
    dx -= CELL * rintf(dx / CELL); dy -= CELL * rintf(dy / CELL); dz -= CELL * rintf(dz / CELL);
    float r = sqrtf(dx * dx + dy * dy + dz * dz);
    float inv = 1.0f / fmaxf(r, 1e-12f);
    float fm;
    if (r <= r0) fm = tf[0];
    else if (r >= rend) fm = tf[N_TABLE - 1];
    else {
        float t = (r - r0) * inv_dr;
        int idx = min(max((int)t, 0), N_TABLE - 2);
        if (r < tr[idx]) idx = max(idx - 1, 0);
        else if (r >= tr[idx + 1]) idx = min(idx + 1, N_TABLE - 2);
        float rl = tr[idx], rh = tr[idx + 1];
        fm = tf[idx] + (r - rl) * (tf[idx + 1] - tf[idx]) / (rh - rl);
    }
    float s = fm * inv;
    float fx = s * dx, fy = s * dy, fz = s * dz;
    atomicAdd(&force[3 * i + 0], fx); atomicAdd(&force[3 * i + 1], fy); atomicAdd(&force[3 * i + 2], fz);
    atomicAdd(&force[3 * j + 0], -fx); atomicAdd(&force[3 * j + 1], -fy); atomicAdd(&force[3 * j + 2], -fz);
}

extern "C" void kernel_launch(void* const* d_in, const int* in_sizes, int n_in,
                              void* d_out, int out_size, void* d_ws, size_t ws_size,
                              hipStream_t stream) {
    const float* q       = (const float*)d_in[0];
    const int2*  nbr     = (const int2*)d_in[1];
    const float* table_r = (const float*)d_in[2];
    const float* table_f = (const float*)d_in[3];
    float*       force   = (float*)d_out;

    const int n_pairs = in_sizes[1] / 2;
    const int n_atoms = in_sizes[0] / 3;

    // workspace layout (256B-aligned)
    size_t off_partial  = 0;
    size_t off_binTotal = off_partial + (size_t)NB * NBLK * 4;           // 4 MB
    size_t off_binBase  = (off_binTotal + (size_t)NB * 4 + 255) & ~255ull;
    size_t off_entries  = (off_binBase + (size_t)(NB + 1) * 4 + 255) & ~255ull;
    size_t need         = off_entries + (size_t)2 * n_pairs * 4;

    if (ws_size < need || n_atoms > NB * 128) {
        // fallback: atomic path
        hipMemsetAsync(d_out, 0, (size_t)out_size * sizeof(float), stream);
        int blocks = (n_pairs + THREADS - 1) / THREADS;
        pair_force_atomic_kernel<<<blocks, THREADS, 0, stream>>>(q, nbr, table_r, table_f, force, n_pairs);
        return;
    }

    char* ws = (char*)d_ws;
    uint* partial  = (uint*)(ws + off_partial);
    uint* binTotal = (uint*)(ws + off_binTotal);
    uint* binBase  = (uint*)(ws + off_binBase);
    uint* entries  = (uint*)(ws + off_entries);

    int ppb = (n_pairs + NBLK - 1) / NBLK;

    hist_kernel<<<NBLK, THREADS, 0, stream>>>(nbr, partial, n_pairs, ppb);
    scan_rows_kernel<<<NB, THREADS, 0, stream>>>(partial, binTotal);
    scan_totals_kernel<<<1, THREADS, 0, stream>>>(binTotal, binBase);
    scatter_kernel<<<NBLK, THREADS, 0, stream>>>(nbr, partial, binBase, entries, n_pairs, ppb);
    reduce_kernel<<<NB, 512, 0, stream>>>(q, table_r, table_f, binBase, entries, force, n_atoms);
}

// Round 3
// 419.712 us; speedup vs baseline: 4.4920x; 1.0588x over previous
//
#include <hip/hip_runtime.h>

#define CELL 50.0f
#define N_TABLE 1024
#define NB 1024            // buckets of 128 atoms each (max 131072 atoms)
#define NBLK 1024          // histogram/scatter blocks
#define THREADS 256
#define RED_THREADS 512
#define NREP 8             // one acc replica per wave in reduce

typedef unsigned int uint;

// ---------------- K0: pack q into float4 ----------------
__global__ __launch_bounds__(THREADS) void pack_q4_kernel(
    const float* __restrict__ q, float4* __restrict__ q4, int n_atoms)
{
    int i = blockIdx.x * THREADS + threadIdx.x;
    if (i < n_atoms)
        q4[i] = make_float4(q[3 * i], q[3 * i + 1], q[3 * i + 2], 0.0f);
}

// ---------------- K1: per-block bucket histogram (int4 loads) ----------------
__global__ __launch_bounds__(THREADS) void hist_kernel(
    const int2* __restrict__ nbr, uint* __restrict__ partial, int n_pairs, int ppb)
{
    __shared__ uint h[NB];
    for (int k = threadIdx.x; k < NB; k += THREADS) h[k] = 0;
    __syncthreads();
    int start = blockIdx.x * ppb;                 // ppb even -> start even
    int end   = min(start + ppb, n_pairs & ~1);
    const int4* nbr4 = (const int4*)nbr;
    for (int p2 = (start >> 1) + threadIdx.x; p2 < (end >> 1); p2 += THREADS) {
        int4 v = nbr4[p2];
        atomicAdd(&h[((uint)v.x) >> 7], 1u);
        atomicAdd(&h[((uint)v.y) >> 7], 1u);
        atomicAdd(&h[((uint)v.z) >> 7], 1u);
        atomicAdd(&h[((uint)v.w) >> 7], 1u);
    }
    if (blockIdx.x == 0 && threadIdx.x == 0 && (n_pairs & 1)) {
        int2 ij = nbr[n_pairs - 1];
        atomicAdd(&h[((uint)ij.x) >> 7], 1u);
        atomicAdd(&h[((uint)ij.y) >> 7], 1u);
    }
    __syncthreads();
    for (int k = threadIdx.x; k < NB; k += THREADS)
        partial[k * NBLK + blockIdx.x] = h[k];
}

// ---------------- K2a: per-bucket exclusive scan over block partials ----------------
__global__ __launch_bounds__(THREADS) void scan_rows_kernel(
    uint* __restrict__ partial, uint* __restrict__ binTotal)
{
    __shared__ uint s[THREADS];
    int bin = blockIdx.x;
    uint running = 0;
    for (int c = 0; c < NBLK / THREADS; c++) {
        int idx = bin * NBLK + c * THREADS + threadIdx.x;
        uint v = partial[idx];
        s[threadIdx.x] = v;
        __syncthreads();
        for (int off = 1; off < THREADS; off <<= 1) {
            uint t = (threadIdx.x >= (uint)off) ? s[threadIdx.x - off] : 0u;
            __syncthreads();
            s[threadIdx.x] += t;
            __syncthreads();
        }
        partial[idx] = running + s[threadIdx.x] - v;   // exclusive within bin
        uint csum = s[THREADS - 1];
        __syncthreads();
        running += csum;
    }
    if (threadIdx.x == 0) binTotal[bin] = running;
}

// ---------------- K2b: exclusive scan of bucket totals ----------------
__global__ __launch_bounds__(THREADS) void scan_totals_kernel(
    const uint* __restrict__ binTotal, uint* __restrict__ binBase)
{
    __shared__ uint s[THREADS];
    uint v[4];
    uint sum = 0;
    int base = threadIdx.x * 4;
    for (int k = 0; k < 4; k++) { v[k] = binTotal[base + k]; sum += v[k]; }
    s[threadIdx.x] = sum;
    __syncthreads();
    for (int off = 1; off < THREADS; off <<= 1) {
        uint t = (threadIdx.x >= (uint)off) ? s[threadIdx.x - off] : 0u;
        __syncthreads();
        s[threadIdx.x] += t;
        __syncthreads();
    }
    uint run = s[threadIdx.x] - sum;
    for (int k = 0; k < 4; k++) { binBase[base + k] = run; run += v[k]; }
    if (threadIdx.x == THREADS - 1) binBase[NB] = run;
}

// ---------------- K3: scatter packed entries (int4 loads) ----------------
// entry = (other_atom << 7) | (self_atom & 127); self's bucket = self >> 7.
__global__ __launch_bounds__(THREADS) void scatter_kernel(
    const int2* __restrict__ nbr, const uint* __restrict__ partial,
    const uint* __restrict__ binBase, uint* __restrict__ entries,
    int n_pairs, int ppb)
{
    __shared__ uint cur[NB];
    for (int k = threadIdx.x; k < NB; k += THREADS)
        cur[k] = binBase[k] + partial[k * NBLK + blockIdx.x];
    __syncthreads();
    int start = blockIdx.x * ppb;
    int end   = min(start + ppb, n_pairs & ~1);
    const int4* nbr4 = (const int4*)nbr;
    for (int p2 = (start >> 1) + threadIdx.x; p2 < (end >> 1); p2 += THREADS) {
        int4 v = nbr4[p2];
        uint i0 = (uint)v.x, j0 = (uint)v.y, i1 = (uint)v.z, j1 = (uint)v.w;
        uint p;
        p = atomicAdd(&cur[i0 >> 7], 1u); entries[p] = (j0 << 7) | (i0 & 127u);
        p = atomicAdd(&cur[j0 >> 7], 1u); entries[p] = (i0 << 7) | (j0 & 127u);
        p = atomicAdd(&cur[i1 >> 7], 1u); entries[p] = (j1 << 7) | (i1 & 127u);
        p = atomicAdd(&cur[j1 >> 7], 1u); entries[p] = (i1 << 7) | (j1 & 127u);
    }
    if (blockIdx.x == 0 && threadIdx.x == 0 && (n_pairs & 1)) {
        int2 ij = nbr[n_pairs - 1];
        uint i = (uint)ij.x, j = (uint)ij.y;
        uint p;
        p = atomicAdd(&cur[i >> 7], 1u); entries[p] = (j << 7) | (i & 127u);
        p = atomicAdd(&cur[j >> 7], 1u); entries[p] = (i << 7) | (j & 127u);
    }
}

// ---------------- K4: per-bucket reduce ----------------
__global__ __launch_bounds__(RED_THREADS) void reduce_kernel(
    const float* __restrict__ q, const float4* __restrict__ q4,
    const float* __restrict__ table_r, const float* __restrict__ table_f,
    const uint* __restrict__ binBase, const uint* __restrict__ entries,
    float* __restrict__ force, int n_atoms, int use_q4)
{
    __shared__ float2 tfp[N_TABLE];        // (f[i], f[i+1]-f[i])
    __shared__ float4 qs[128];
    __shared__ float  acc[NREP * 384];

    int b = blockIdx.x;
    int atomBase = b << 7;
    if (atomBase >= n_atoms) return;
    int nA = min(128, n_atoms - atomBase);

    const float r0     = table_r[0];
    const float rend   = table_r[N_TABLE - 1];
    const float inv_dr = (float)(N_TABLE - 1) / (rend - r0);

    for (int k = threadIdx.x; k < N_TABLE - 1; k += RED_THREADS) {
        float a = table_f[k], c = table_f[k + 1];
        tfp[k] = make_float2(a, c - a);
    }
    for (int k = threadIdx.x; k < nA; k += RED_THREADS) {
        if (use_q4) qs[k] = q4[atomBase + k];
        else qs[k] = make_float4(q[(atomBase + k) * 3], q[(atomBase + k) * 3 + 1],
                                 q[(atomBase + k) * 3 + 2], 0.0f);
    }
    for (int k = threadIdx.x; k < NREP * 384; k += RED_THREADS) acc[k] = 0.0f;
    __syncthreads();

    float* myacc = &acc[((threadIdx.x >> 6) & (NREP - 1)) * 384];

    uint e0 = binBase[b], e1 = binBase[b + 1];
    uint count = e1 - e0;
    uint nmain = count & ~(uint)(4 * RED_THREADS - 1);

#define PROC(V)                                                              \
    {                                                                        \
        uint v = (V);                                                        \
        int local = (int)(v & 127u);                                         \
        int other = (int)(v >> 7);                                           \
        float ox, oy, oz;                                                    \
        if (use_q4) { float4 t4 = q4[other]; ox = t4.x; oy = t4.y; oz = t4.z; } \
        else { ox = q[3 * other]; oy = q[3 * other + 1]; oz = q[3 * other + 2]; } \
        float4 m = qs[local];                                                \
        float dx = m.x - ox, dy = m.y - oy, dz = m.z - oz;                   \
        dx -= CELL * rintf(dx / CELL);                                       \
        dy -= CELL * rintf(dy / CELL);                                       \
        dz -= CELL * rintf(dz / CELL);                                       \
        float r   = sqrtf(dx * dx + dy * dy + dz * dz);                      \
        float inv = 1.0f / fmaxf(r, 1e-12f);                                 \
        float t   = (r - r0) * inv_dr;                                       \
        t = fminf(fmaxf(t, 0.0f), 1023.0f);                                  \
        int idx = min((int)t, N_TABLE - 2);                                  \
        float frac = t - (float)idx;                                         \
        float2 tp = tfp[idx];                                                \
        float s = (tp.x + frac * tp.y) * inv;                                \
        atomicAdd(&myacc[local * 3 + 0], s * dx);                            \
        atomicAdd(&myacc[local * 3 + 1], s * dy);                            \
        atomicAdd(&myacc[local * 3 + 2], s * dz);                            \
    }

    for (uint base = 0; base < nmain; base += 4 * RED_THREADS) {
        uint ea = e0 + base + threadIdx.x;
        uint v0 = entries[ea];
        uint v1 = entries[ea + RED_THREADS];
        uint v2 = entries[ea + 2 * RED_THREADS];
        uint v3 = entries[ea + 3 * RED_THREADS];
        PROC(v0); PROC(v1); PROC(v2); PROC(v3);
    }
    for (uint e = e0 + nmain + threadIdx.x; e < e1; e += RED_THREADS)
        PROC(entries[e]);
#undef PROC

    __syncthreads();
    for (int k = threadIdx.x; k < nA * 3; k += RED_THREADS) {
        float s = 0.0f;
        #pragma unroll
        for (int rp = 0; rp < NREP; rp++) s += acc[rp * 384 + k];
        force[atomBase * 3 + k] = s;
    }
}

// ---------------- fallback: proven global-atomic kernel ----------------
__global__ __launch_bounds__(THREADS) void pair_force_atomic_kernel(
    const float* __restrict__ q, const int2* __restrict__ nbr,
    const float* __restrict__ table_r, const float* __restrict__ table_f,
    float* __restrict__ force, int n_pairs)
{
    __shared__ float tr[N_TABLE];
    __shared__ float tf[N_TABLE];
    for (int k = threadIdx.x; k < N_TABLE; k += THREADS) { tr[k] = table_r[k]; tf[k] = table_f[k]; }
    __syncthreads();
    const float r0 = tr[0], rend = tr[N_TABLE - 1];
    const float inv_dr = (float)(N_TABLE - 1) / (rend - r0);
    int p = blockIdx.x * THREADS + threadIdx.x;
    if (p >= n_pairs) return;
    int2 ij = nbr[p];
    int i = ij.x, j = ij.y;
    float dx = q[3 * i] - q[3 * j], dy = q[3 * i + 1] - q[3 * j + 1], dz = q[3 * i + 2] - q[3 * j + 2];
    dx -= CELL * rintf(dx / CELL); dy -= CELL * rintf(dy / CELL); dz -= CELL * rintf(dz / CELL);
    float r = sqrtf(dx * dx + dy * dy + dz * dz);
    float inv = 1.0f / fmaxf(r, 1e-12f);
    float fm;
    if (r <= r0) fm = tf[0];
    else if (r >= rend) fm = tf[N_TABLE - 1];
    else {
        float t = (r - r0) * inv_dr;
        int idx = min(max((int)t, 0), N_TABLE - 2);
        if (r < tr[idx]) idx = max(idx - 1, 0);
        else if (r >= tr[idx + 1]) idx = min(idx + 1, N_TABLE - 2);
        float rl = tr[idx], rh = tr[idx + 1];
        fm = tf[idx] + (r - rl) * (tf[idx + 1] - tf[idx]) / (rh - rl);
    }
    float s = fm * inv;
    float fx = s * dx, fy = s * dy, fz = s * dz;
    atomicAdd(&force[3 * i + 0], fx); atomicAdd(&force[3 * i + 1], fy); atomicAdd(&force[3 * i + 2], fz);
    atomicAdd(&force[3 * j + 0], -fx); atomicAdd(&force[3 * j + 1], -fy); atomicAdd(&force[3 * j + 2], -fz);
}

extern "C" void kernel_launch(void* const* d_in, const int* in_sizes, int n_in,
                              void* d_out, int out_size, void* d_ws, size_t ws_size,
                              hipStream_t stream) {
    const float* q       = (const float*)d_in[0];
    const int2*  nbr     = (const int2*)d_in[1];
    const float* table_r = (const float*)d_in[2];
    const float* table_f = (const float*)d_in[3];
    float*       force   = (float*)d_out;

    const int n_pairs = in_sizes[1] / 2;
    const int n_atoms = in_sizes[0] / 3;

    // workspace layout (256B-aligned)
    size_t off_partial  = 0;
    size_t off_binTotal = off_partial + (size_t)NB * NBLK * 4;           // 4 MB
    size_t off_binBase  = (off_binTotal + (size_t)NB * 4 + 255) & ~255ull;
    size_t off_entries  = (off_binBase + (size_t)(NB + 1) * 4 + 255) & ~255ull;
    size_t off_q4       = (off_entries + (size_t)2 * n_pairs * 4 + 255) & ~255ull;
    size_t need_base    = off_q4;                       // without q4
    size_t need_q4      = off_q4 + (size_t)n_atoms * 16;

    if (ws_size < need_base || n_atoms > NB * 128) {
        hipMemsetAsync(d_out, 0, (size_t)out_size * sizeof(float), stream);
        int blocks = (n_pairs + THREADS - 1) / THREADS;
        pair_force_atomic_kernel<<<blocks, THREADS, 0, stream>>>(q, nbr, table_r, table_f, force, n_pairs);
        return;
    }

    char* ws = (char*)d_ws;
    uint*   partial  = (uint*)(ws + off_partial);
    uint*   binTotal = (uint*)(ws + off_binTotal);
    uint*   binBase  = (uint*)(ws + off_binBase);
    uint*   entries  = (uint*)(ws + off_entries);
    float4* q4       = (float4*)(ws + off_q4);
    int use_q4 = (ws_size >= need_q4) ? 1 : 0;

    int ppb = (((n_pairs + NBLK - 1) / NBLK) + 1) & ~1;   // even pairs per block

    if (use_q4) {
        int pb = (n_atoms + THREADS - 1) / THREADS;
        pack_q4_kernel<<<pb, THREADS, 0, stream>>>(q, q4, n_atoms);
    }
    hist_kernel<<<NBLK, THREADS, 0, stream>>>(nbr, partial, n_pairs, ppb);
    scan_rows_kernel<<<NB, THREADS, 0, stream>>>(partial, binTotal);
    scan_totals_kernel<<<1, THREADS, 0, stream>>>(binTotal, binBase);
    scatter_kernel<<<NBLK, THREADS, 0, stream>>>(nbr, partial, binBase, entries, n_pairs, ppb);
    reduce_kernel<<<NB, RED_THREADS, 0, stream>>>(q, q4, table_r, table_f, binBase, entries, force, n_atoms, use_q4);
}